// Round 11
// baseline (307.468 us; speedup 1.0000x reference)
//
#include <hip/hip_runtime.h>
#include <hip/hip_bf16.h>

typedef __attribute__((ext_vector_type(8))) short bf16x8;
typedef __attribute__((ext_vector_type(4))) float f32x4;

#define GLOBAL_CAST(p) (const __attribute__((address_space(1))) void*)(p)
#define LDS_CAST(p)    (__attribute__((address_space(3))) void*)(p)

static __device__ __forceinline__ unsigned short f2bf(float f) {
    union { float f; unsigned int u; } v; v.f = f;
    unsigned int u = v.u;
    unsigned int r = (u + 0x7FFFu + ((u >> 16) & 1u)) >> 16;   // RNE
    return (unsigned short)r;
}

// ---------------------------------------------------------------------------
// Kernel 1: per-row scale = max(mean(|w|), eps); q = ternary(w) as bf16 bits.
// ---------------------------------------------------------------------------
__global__ __launch_bounds__(256) void scale_quant_kernel(
    const float* __restrict__ w, float* __restrict__ scale,
    unsigned short* __restrict__ q, int K)
{
    const int row = blockIdx.x;
    const int tid = threadIdx.x;
    const float* wrow = w + (size_t)row * K;

    float s = 0.f;
    const int nvec = K >> 2;
    const float4* wv = (const float4*)wrow;
    for (int i = tid; i < nvec; i += blockDim.x) {
        float4 v = wv[i];
        s += fabsf(v.x) + fabsf(v.y) + fabsf(v.z) + fabsf(v.w);
    }
    #pragma unroll
    for (int off = 32; off > 0; off >>= 1) s += __shfl_down(s, off);

    __shared__ float red[4];
    const int lane = tid & 63, wid = tid >> 6;
    if (lane == 0) red[wid] = s;
    __syncthreads();
    const float total = red[0] + red[1] + red[2] + red[3];
    const float sc = fmaxf(total / (float)K, 1e-6f);
    const float thr = sc * 0.75f;
    if (tid == 0) scale[row] = sc;

    if (q != nullptr) {
        ushort4* qv = (ushort4*)(q + (size_t)row * K);
        for (int i = tid; i < nvec; i += blockDim.x) {
            float4 v = wv[i];
            ushort4 o;
            o.x = (v.x >= thr) ? 0x3F80u : ((v.x <= -thr) ? 0xBF80u : 0u);
            o.y = (v.y >= thr) ? 0x3F80u : ((v.y <= -thr) ? 0xBF80u : 0u);
            o.z = (v.z >= thr) ? 0x3F80u : ((v.z <= -thr) ? 0xBF80u : 0u);
            o.w = (v.w >= thr) ? 0x3F80u : ((v.w <= -thr) ? 0xBF80u : 0u);
            qv[i] = o;
        }
    }
}

// ---------------------------------------------------------------------------
// Kernel 2: x fp32 -> bf16 (RNE), 8 elems/thread.
// ---------------------------------------------------------------------------
__global__ __launch_bounds__(256) void convert_x_kernel(
    const float* __restrict__ x, unsigned short* __restrict__ xb, long n)
{
    long i = ((long)blockIdx.x * blockDim.x + threadIdx.x) * 8;
    if (i + 8 > n) return;
    float4 a = *(const float4*)(x + i);
    float4 b = *(const float4*)(x + i + 4);
    ushort4 lo, hi;
    lo.x = f2bf(a.x); lo.y = f2bf(a.y); lo.z = f2bf(a.z); lo.w = f2bf(a.w);
    hi.x = f2bf(b.x); hi.y = f2bf(b.y); hi.z = f2bf(b.z); hi.w = f2bf(b.w);
    *(ushort4*)(xb + i)     = lo;
    *(ushort4*)(xb + i + 4) = hi;
}

// ---------------------------------------------------------------------------
// Kernel 3: 256x256 bf16 GEMM, 16x16x32 MFMA, depth-3 region rotation with
// PHASE-LEVEL A-READ-AHEAD (register double-banking).
//   out[m][n] = scale[n] * sum_k Xb[m][k]*Qb[n][k] + bias[n]
// 512 thr = 8 waves (2M x 4N); per-wave 128x64 out = acc[8][4].
// LDS 128 KiB, 4 contiguous regions {A 16K | B 16K}; region(phi) base
//   dx(phi) = ((phi&1)<<14) | (((phi>>1)&1)<<16); region = one k-half of a
//   K-tile, [256 rows][4 slots x 16B] row stride 64 B; staging dest LINEAR,
//   source column pre-swizzled slot s ^ ((r>>1)&3) (0 conflicts, r10).
// Phase phi: { rd b(phi) [4, FIRST in queue] | rd a(phi+1) -> other bank [8] |
//   stage region phi+3 | sched_barrier | setprio(1) 32 MFMA(bank phi&1)
//   setprio(0) | vmcnt(4) | sched_barrier | s_barrier }.
// MFMA waits only lgkmcnt(8) (b oldest), so the 8 a-ahead reads run on the
// LDS pipe UNDER the MFMA cluster -> LDS/matrix pipe overlap.
// Validity: vmcnt(4)+barrier at end of phase q => region q+2 globally valid;
// phase p reads regions p (b) and p+1 (a) - both valid. Overwrite target =
// region phi-1 (mod 4), last read before the previous barrier.
// ---------------------------------------------------------------------------
#define BM 256
#define BN 256
#define BK 64

__global__ __launch_bounds__(512, 2) void gemm256_kernel(
    const unsigned short* __restrict__ Xb,   // [M][K] bf16 bits
    const unsigned short* __restrict__ Qb,   // [N][K] bf16 bits
    const float* __restrict__ scale,
    const float* __restrict__ bias,
    float* __restrict__ out, int M, int N, int K)
{
    __shared__ __align__(16) char lds[131072];

    const int tid  = threadIdx.x;
    const int lane = tid & 63;
    const int wid  = tid >> 6;       // 0..7
    const int wm   = wid >> 2;       // 0..1  (M half of tile)
    const int wn   = wid & 3;        // 0..3  (N quarter)
    const int kh   = lane >> 4;      // 0..3
    const int lr   = lane & 15;

    // XCD-bijective swizzle (grid % 8 == 0 guaranteed by host gate)
    int bid = blockIdx.x;
    const int nwg = gridDim.x;
    if ((nwg & 7) == 0) { const int cpx = nwg >> 3; bid = (bid & 7) * cpx + (bid >> 3); }
    const int nbn = N / BN;
    const int tm = bid / nbn, tn = bid % nbn;
    const int arow0 = tm * BM;
    const int brow0 = tn * BN;
    const int NT = K / BK;

    // ---- LDS read offsets (region-base-relative) ----
    unsigned aoff[8], boff[4];
    #pragma unroll
    for (int mf = 0; mf < 8; ++mf) {
        const int row = wm * 128 + mf * 16 + lr;
        aoff[mf] = (unsigned)(row * 64 + ((kh ^ ((row >> 1) & 3)) << 4));
    }
    #pragma unroll
    for (int nf = 0; nf < 4; ++nf) {
        const int row = wn * 64 + nf * 16 + lr;
        boff[nf] = 0x8000u | (unsigned)(row * 64 + ((kh ^ ((row >> 1) & 3)) << 4));
    }

    // ---- staging: linear dest, pre-swizzled global source column ----
    const int r0 = tid >> 2;
    const int s0 = tid & 3;
    const int scol = (s0 ^ ((r0 >> 1) & 3)) << 3;
    const unsigned sdA0 = (unsigned)(tid * 16);
    const unsigned sdA1 = (unsigned)((tid + 512) * 16);
    const unsigned sdB0 = 0x8000u | sdA0;
    const unsigned sdB1 = 0x8000u | sdA1;

    const unsigned short* aBase0 = Xb + (size_t)(arow0 + r0) * K + scol;
    const unsigned short* aBase1 = Xb + (size_t)(arow0 + r0 + 128) * K + scol;
    const unsigned short* bBase0 = Qb + (size_t)(brow0 + r0) * K + scol;
    const unsigned short* bBase1 = Qb + (size_t)(brow0 + r0 + 128) * K + scol;

    // ---- prologue: stage regions 0,1,2; vmcnt(4) -> regions 0,1 landed ----
    #pragma unroll
    for (int rho = 0; rho < 3; ++rho) {
        const unsigned dxs = (unsigned)((rho & 1) << 14) | ((unsigned)((rho >> 1) & 1) << 16);
        const int ke = rho * 32;
        __builtin_amdgcn_global_load_lds(GLOBAL_CAST(aBase0 + ke), LDS_CAST(lds + (dxs | sdA0)), 16, 0, 0);
        __builtin_amdgcn_global_load_lds(GLOBAL_CAST(aBase1 + ke), LDS_CAST(lds + (dxs | sdA1)), 16, 0, 0);
        __builtin_amdgcn_global_load_lds(GLOBAL_CAST(bBase0 + ke), LDS_CAST(lds + (dxs | sdB0)), 16, 0, 0);
        __builtin_amdgcn_global_load_lds(GLOBAL_CAST(bBase1 + ke), LDS_CAST(lds + (dxs | sdB1)), 16, 0, 0);
    }
    const unsigned short* aS0 = aBase0 + 96;   // next stage = region 3
    const unsigned short* aS1 = aBase1 + 96;
    const unsigned short* bS0 = bBase0 + 96;
    const unsigned short* bS1 = bBase1 + 96;

    asm volatile("s_waitcnt vmcnt(4)" ::: "memory");
    __builtin_amdgcn_sched_barrier(0);
    __builtin_amdgcn_s_barrier();

    f32x4 acc[8][4] = {};
    bf16x8 aA[8], aB[8], b[4];

    // pre-read a(0) into bank A (region 0)
    #pragma unroll
    for (int mf = 0; mf < 8; ++mf)
        aA[mf] = *(const bf16x8*)(lds + aoff[mf]);

    #define STAGE4(DXS) {                                                           \
        __builtin_amdgcn_global_load_lds(GLOBAL_CAST(aS0), LDS_CAST(lds + ((DXS) | sdA0)), 16, 0, 0); \
        __builtin_amdgcn_global_load_lds(GLOBAL_CAST(aS1), LDS_CAST(lds + ((DXS) | sdA1)), 16, 0, 0); \
        __builtin_amdgcn_global_load_lds(GLOBAL_CAST(bS0), LDS_CAST(lds + ((DXS) | sdB0)), 16, 0, 0); \
        __builtin_amdgcn_global_load_lds(GLOBAL_CAST(bS1), LDS_CAST(lds + ((DXS) | sdB1)), 16, 0, 0); \
        aS0 += 32; aS1 += 32; bS0 += 32; bS1 += 32; }
    #define MFMA32(ACUR)                                                            \
        _Pragma("unroll")                                                           \
        for (int mf = 0; mf < 8; ++mf)                                              \
            _Pragma("unroll")                                                       \
            for (int nf = 0; nf < 4; ++nf)                                          \
                acc[mf][nf] = __builtin_amdgcn_mfma_f32_16x16x32_bf16(              \
                    ACUR[mf], b[nf], acc[mf][nf], 0, 0, 0);

    for (int t = 0; t < NT; ++t) {
        const unsigned bufbit = (unsigned)(t & 1) << 16;

        // ======== phase cc=0 (phi=2t): consume aA, prefetch aB ========
        {
            const unsigned dxr = bufbit;
            #pragma unroll
            for (int nf = 0; nf < 4; ++nf)                       // b FIRST (oldest)
                b[nf] = *(const bf16x8*)(lds + (dxr | boff[nf]));
            const unsigned dxn = bufbit | 0x4000u;               // region 2t+1
            #pragma unroll
            for (int mf = 0; mf < 8; ++mf)
                aB[mf] = *(const bf16x8*)(lds + (dxn | aoff[mf]));
            if (t <= NT - 2) { const unsigned dxs = 0x4000u | (bufbit ^ 0x10000u); STAGE4(dxs) }  // region 2t+3
            __builtin_amdgcn_sched_barrier(0);
            __builtin_amdgcn_s_setprio(1);
            MFMA32(aA)
            __builtin_amdgcn_s_setprio(0);
            if (t < NT - 1) { asm volatile("s_waitcnt vmcnt(4)" ::: "memory"); }
            __builtin_amdgcn_sched_barrier(0);
            __builtin_amdgcn_s_barrier();
        }

        // ======== phase cc=1 (phi=2t+1): consume aB, prefetch aA ========
        {
            const unsigned dxr = bufbit | 0x4000u;
            #pragma unroll
            for (int nf = 0; nf < 4; ++nf)
                b[nf] = *(const bf16x8*)(lds + (dxr | boff[nf]));
            if (t < NT - 1) {
                const unsigned dxn = bufbit ^ 0x10000u;          // region 2t+2
                #pragma unroll
                for (int mf = 0; mf < 8; ++mf)
                    aA[mf] = *(const bf16x8*)(lds + (dxn | aoff[mf]));
            }
            if (t <= NT - 3) { const unsigned dxs = bufbit; STAGE4(dxs) }            // region 2t+4
            __builtin_amdgcn_sched_barrier(0);
            __builtin_amdgcn_s_setprio(1);
            MFMA32(aB)
            __builtin_amdgcn_s_setprio(0);
            if (t < NT - 2)       { asm volatile("s_waitcnt vmcnt(4)" ::: "memory"); }
            else if (t == NT - 2) { asm volatile("s_waitcnt vmcnt(0)" ::: "memory"); }
            __builtin_amdgcn_sched_barrier(0);
            __builtin_amdgcn_s_barrier();
        }
    }
    #undef STAGE4
    #undef MFMA32

    // epilogue: out = scale[n]*acc + bias[n]; D layout col=lane&15, row=(lane>>4)*4+r
    #pragma unroll
    for (int nf = 0; nf < 4; ++nf) {
        const int gn = brow0 + wn * 64 + nf * 16 + lr;
        const float sc = scale[gn];
        const float bs = bias[gn];
        #pragma unroll
        for (int mf = 0; mf < 8; ++mf) {
            const size_t gm = (size_t)arow0 + wm * 128 + mf * 16 + kh * 4;
            #pragma unroll
            for (int r = 0; r < 4; ++r)
                out[(gm + r) * (size_t)N + gn] = acc[mf][nf][r] * sc + bs;
        }
    }
}

// ---------------------------------------------------------------------------
// Fallback: fp32 smem-tiled GEMM, quantize on the fly.
// ---------------------------------------------------------------------------
__global__ __launch_bounds__(256) void fb_gemm_kernel(
    const float* __restrict__ X, const float* __restrict__ W,
    const float* __restrict__ scale, const float* __restrict__ bias,
    float* __restrict__ out, int M, int N, int K)
{
    __shared__ float xs[16][16];
    __shared__ float qs[16][17];
    const int tx = threadIdx.x & 15, ty = threadIdx.x >> 4;
    const int m = blockIdx.y * 16 + ty;
    const int n = blockIdx.x * 16 + tx;
    const int nrow = blockIdx.x * 16 + ty;
    const int mL = min(m, M - 1);
    const int nrowL = min(nrow, N - 1);
    const float thr = scale[nrowL] * 0.75f;
    float acc = 0.f;
    for (int k0 = 0; k0 < K; k0 += 16) {
        xs[ty][tx] = X[(size_t)mL * K + k0 + tx];
        const float w = W[(size_t)nrowL * K + k0 + tx];
        qs[ty][tx] = (w >= thr) ? 1.f : ((w <= -thr) ? -1.f : 0.f);
        __syncthreads();
        #pragma unroll
        for (int kk = 0; kk < 16; ++kk) acc += xs[ty][kk] * qs[tx][kk];
        __syncthreads();
    }
    if (m < M && n < N) out[(size_t)m * N + n] = scale[n] * acc + bias[n];
}

// ---------------------------------------------------------------------------
extern "C" void kernel_launch(void* const* d_in, const int* in_sizes, int n_in,
                              void* d_out, int out_size, void* d_ws, size_t ws_size,
                              hipStream_t stream)
{
    const float* x    = (const float*)d_in[0];
    const float* w    = (const float*)d_in[1];
    const float* bias = (const float*)d_in[2];
    float* out = (float*)d_out;

    const int N = in_sizes[2];             // OUT
    const int K = in_sizes[1] / N;         // IN
    const int M = in_sizes[0] / K;         // B

    const size_t scaleBytes = (size_t)N * sizeof(float);
    const size_t qOff = (scaleBytes + 255) & ~(size_t)255;
    const size_t xOff = qOff + (size_t)N * K * sizeof(unsigned short);
    const size_t need = xOff + (size_t)M * K * sizeof(unsigned short);

    float* scale = (float*)d_ws;

    const bool fast = (ws_size >= need) &&
                      (M % BM == 0) && (N % BN == 0) && (K % BK == 0) &&
                      (K / BK >= 4) &&
                      (((M / BM) * (N / BN)) % 8 == 0);

    if (fast) {
        unsigned short* q  = (unsigned short*)((char*)d_ws + qOff);
        unsigned short* xb = (unsigned short*)((char*)d_ws + xOff);

        scale_quant_kernel<<<N, 256, 0, stream>>>(w, scale, q, K);

        const long nx = (long)M * K;
        const int cvtBlocks = (int)((nx + 2047) / 2048);
        convert_x_kernel<<<cvtBlocks, 256, 0, stream>>>(x, xb, nx);

        const int grid = (M / BM) * (N / BN);
        gemm256_kernel<<<grid, 512, 0, stream>>>(xb, q, scale, bias, out, M, N, K);
    } else {
        scale_quant_kernel<<<N, 256, 0, stream>>>(w, scale, nullptr, K);
        dim3 g((N + 15) / 16, (M + 15) / 16);
        fb_gemm_kernel<<<g, 256, 0, stream>>>(x, w, scale, bias, out, M, N, K);
    }
}

// Round 12
// 190.445 us; speedup vs baseline: 1.6145x; 1.6145x over previous
//
#include <hip/hip_runtime.h>
#include <hip/hip_bf16.h>

typedef __attribute__((ext_vector_type(4))) int i32x4;

#define GLOBAL_CAST(p) (const __attribute__((address_space(1))) void*)(p)
#define LDS_CAST(p)    (__attribute__((address_space(3))) void*)(p)

// ---------------------------------------------------------------------------
// Kernel 1: per-row scale = max(mean(|w|), eps); q = ternary(w) as i8.
// ---------------------------------------------------------------------------
__global__ __launch_bounds__(256) void scale_quant_kernel(
    const float* __restrict__ w, float* __restrict__ scale,
    signed char* __restrict__ q, int K)
{
    const int row = blockIdx.x;
    const int tid = threadIdx.x;
    const float* wrow = w + (size_t)row * K;

    float s = 0.f;
    const int nvec = K >> 2;
    const float4* wv = (const float4*)wrow;
    for (int i = tid; i < nvec; i += blockDim.x) {
        float4 v = wv[i];
        s += fabsf(v.x) + fabsf(v.y) + fabsf(v.z) + fabsf(v.w);
    }
    #pragma unroll
    for (int off = 32; off > 0; off >>= 1) s += __shfl_down(s, off);

    __shared__ float red[4];
    const int lane = tid & 63, wid = tid >> 6;
    if (lane == 0) red[wid] = s;
    __syncthreads();
    const float total = red[0] + red[1] + red[2] + red[3];
    const float sc = fmaxf(total / (float)K, 1e-6f);
    const float thr = sc * 0.75f;
    if (tid == 0) scale[row] = sc;

    if (q != nullptr) {
        char4* qv = (char4*)(q + (size_t)row * K);
        for (int i = tid; i < nvec; i += blockDim.x) {
            float4 v = wv[i];
            char4 o;
            o.x = (v.x >= thr) ? 1 : ((v.x <= -thr) ? -1 : 0);
            o.y = (v.y >= thr) ? 1 : ((v.y <= -thr) ? -1 : 0);
            o.z = (v.z >= thr) ? 1 : ((v.z <= -thr) ? -1 : 0);
            o.w = (v.w >= thr) ? 1 : ((v.w <= -thr) ? -1 : 0);
            qv[i] = o;
        }
    }
}

// ---------------------------------------------------------------------------
// Kernel 2: per-row symmetric i8 quantization of x.
//   sx[row] = absmax/127;  xq = round(x * 127/absmax)
// ---------------------------------------------------------------------------
__global__ __launch_bounds__(256) void x_quant_kernel(
    const float* __restrict__ x, float* __restrict__ sx,
    signed char* __restrict__ xq, int K)
{
    const int row = blockIdx.x;
    const int tid = threadIdx.x;
    const float4* xv = (const float4*)(x + (size_t)row * K);
    const int nvec = K >> 2;

    float am = 0.f;
    for (int i = tid; i < nvec; i += blockDim.x) {
        float4 v = xv[i];
        am = fmaxf(am, fmaxf(fmaxf(fabsf(v.x), fabsf(v.y)), fmaxf(fabsf(v.z), fabsf(v.w))));
    }
    #pragma unroll
    for (int off = 32; off > 0; off >>= 1) am = fmaxf(am, __shfl_down(am, off));

    __shared__ float red[4];
    const int lane = tid & 63, wid = tid >> 6;
    if (lane == 0) red[wid] = am;
    __syncthreads();
    const float amax = fmaxf(fmaxf(red[0], red[1]), fmaxf(red[2], red[3]));
    const float inv = (amax > 0.f) ? (127.f / amax) : 0.f;
    if (tid == 0) sx[row] = amax * (1.f / 127.f);

    char4* qv = (char4*)(xq + (size_t)row * K);
    for (int i = tid; i < nvec; i += blockDim.x) {
        float4 v = xv[i];   // L2/L3-hot re-read
        char4 o;
        o.x = (signed char)__float2int_rn(v.x * inv);
        o.y = (signed char)__float2int_rn(v.y * inv);
        o.z = (signed char)__float2int_rn(v.z * inv);
        o.w = (signed char)__float2int_rn(v.w * inv);
        qv[i] = o;
    }
}

// ---------------------------------------------------------------------------
// Kernel 3: 256x256 i8 GEMM (mfma_i32_16x16x64_i8), r4 schedule verbatim.
//   out[m][n] = sx[m]*scale[n] * (sum_k xq[m][k]*q[n][k]) + bias[n]
// 512 thr = 8 waves (2M x 4N); per-wave 128x64 out = acc[8][4] i32x4.
// LDS 128 KiB: 2 dbuf x {A 256x128i8 | B 256x128i8} (32 KB each; row = 128 B,
// identical byte geometry to the r4 bf16 kernel -> same proven-0-conflict
// chunk swizzle: slot s of row r holds global 16B-chunk s ^ (r&7)).
// Per K-tile t (reads from buf tb, DMA writes into buf ta):
//   sec A: stage A(t+1)->ta | rd b0,a-lo | q0 | stage B(t+1)->ta | rd b1 | q1 | bar
//   sec B: rd a-hi | q2 q3 | vmcnt(0) | bar
// Frag: A lane row l&15, 16 contiguous i8 at chunk (l>>4) + 4*ks  (any k-perm
// cancels between A and B). C/D: col=lane&15, row=(lane>>4)*4+reg (m89,
// dtype-independent m121-128). i32 accumulation is exact.
// ---------------------------------------------------------------------------
#define BM 256
#define BN 256
#define BK 128

__global__ __launch_bounds__(512, 2) void gemm256_i8_kernel(
    const signed char* __restrict__ Xq,   // [M][K] i8
    const signed char* __restrict__ Qq,   // [N][K] i8
    const float* __restrict__ sx,         // [M]
    const float* __restrict__ scale,      // [N]
    const float* __restrict__ bias,       // [N]
    float* __restrict__ out, int M, int N, int K)
{
    __shared__ __align__(16) char lds[131072];

    const int tid  = threadIdx.x;
    const int lane = tid & 63;
    const int wid  = tid >> 6;       // 0..7
    const int wm   = wid >> 2;       // 0..1  (M half of tile)
    const int wn   = wid & 3;        // 0..3  (N quarter)
    const int kh   = lane >> 4;      // 0..3
    const int lr   = lane & 15;

    // XCD-bijective swizzle (grid % 8 == 0 guaranteed by host gate)
    int bid = blockIdx.x;
    const int nwg = gridDim.x;
    if ((nwg & 7) == 0) { const int cpx = nwg >> 3; bid = (bid & 7) * cpx + (bid >> 3); }
    const int nbn = N / BN;
    const int tm = bid / nbn, tn = bid % nbn;
    const int arow0 = tm * BM;
    const int brow0 = tn * BN;
    const int NT = K / BK;

    // ---- LDS read byte-offsets (buffer 0; toggle via OR tb) ----
    // chunk = kh + 4*ks; slot = chunk ^ (row&7); row stride 128 B.
    unsigned aoff[2][4], boff[2][2];
    #pragma unroll
    for (int ks = 0; ks < 2; ++ks) {
        const int c = kh + ks * 4;
        #pragma unroll
        for (int mf = 0; mf < 4; ++mf) {
            const int row = wm * 128 + mf * 16 + lr;              // a-lo row
            aoff[ks][mf] = (unsigned)(row * 128 + ((c ^ (row & 7)) << 4));
        }
        #pragma unroll
        for (int nf = 0; nf < 2; ++nf) {
            const int row = wn * 64 + nf * 16 + lr;               // b-lo row
            boff[ks][nf] = (unsigned)(32768 + row * 128 + ((c ^ (row & 7)) << 4));
        }
    }
    // a-hi = +8192 bytes (row+64: same &7 -> same swizzle); b-hi = +4096.

    // ---- stage streams: running global pointers + fixed LDS dest offs ----
    const int r0 = tid >> 3;
    const int c0 = (((tid & 7) ^ (r0 & 7)) << 4);        // i8 elems (16/chunk)
    const int ci1 = 512 + tid;
    const int r1 = ci1 >> 3;
    const int c1 = (((ci1 & 7) ^ (r1 & 7)) << 4);

    const signed char* asrc[2][2];
    const signed char* bsrc[2][2];
    unsigned adst[2][2], bdst[2][2];
    #pragma unroll
    for (int hh = 0; hh < 2; ++hh) {
        asrc[hh][0] = Xq + (size_t)(arow0 + hh * 128 + r0) * K + BK + c0;   // A(t+1)
        asrc[hh][1] = Xq + (size_t)(arow0 + hh * 128 + r1) * K + BK + c1;
        bsrc[hh][0] = Qq + (size_t)(brow0 + hh * 128 + r0) * K + BK + c0;   // B(t+1)
        bsrc[hh][1] = Qq + (size_t)(brow0 + hh * 128 + r1) * K + BK + c1;
        adst[hh][0] = (unsigned)(hh * 16384 + tid * 16);
        adst[hh][1] = (unsigned)(hh * 16384 + ci1 * 16);
        bdst[hh][0] = (unsigned)(32768 + hh * 16384 + tid * 16);
        bdst[hh][1] = (unsigned)(32768 + hh * 16384 + ci1 * 16);
    }

    // ---- prologue: stage tile 0 {A0,A1,B0,B1} into buffer 0 ----
    #pragma unroll
    for (int hh = 0; hh < 2; ++hh) {
        const int rowA = arow0 + hh * 128, rowB = brow0 + hh * 128;
        const signed char* ga0 = Xq + (size_t)(rowA + r0) * K + c0;
        const signed char* ga1 = Xq + (size_t)(rowA + r1) * K + c1;
        const signed char* gb0 = Qq + (size_t)(rowB + r0) * K + c0;
        const signed char* gb1 = Qq + (size_t)(rowB + r1) * K + c1;
        __builtin_amdgcn_global_load_lds(GLOBAL_CAST(ga0), LDS_CAST(lds + adst[hh][0]), 16, 0, 0);
        __builtin_amdgcn_global_load_lds(GLOBAL_CAST(ga1), LDS_CAST(lds + adst[hh][1]), 16, 0, 0);
        __builtin_amdgcn_global_load_lds(GLOBAL_CAST(gb0), LDS_CAST(lds + bdst[hh][0]), 16, 0, 0);
        __builtin_amdgcn_global_load_lds(GLOBAL_CAST(gb1), LDS_CAST(lds + bdst[hh][1]), 16, 0, 0);
    }
    asm volatile("s_waitcnt vmcnt(0)" ::: "memory");
    __builtin_amdgcn_sched_barrier(0);
    __builtin_amdgcn_s_barrier();

    i32x4 acc[8][4] = {};
    i32x4 a[2][4];        // time-shared between M halves
    i32x4 b0[2][2], b1[2][2];

    #define RDA(ks, mf, EX) (*(const i32x4*)(lds + (tb | aoff[ks][mf]) + (EX)))
    #define RDB(ks, nf, EX) (*(const i32x4*)(lds + (tb | boff[ks][nf]) + (EX)))
    #define MFMA16(AR, BR, AI, BJ)                                            \
        _Pragma("unroll")                                                     \
        for (int ks = 0; ks < 2; ++ks)                                        \
            _Pragma("unroll")                                                 \
            for (int mf = 0; mf < 4; ++mf)                                    \
                _Pragma("unroll")                                             \
                for (int nf = 0; nf < 2; ++nf)                                \
                    acc[(AI) + mf][(BJ) + nf] =                               \
                        __builtin_amdgcn_mfma_i32_16x16x64_i8(                \
                            AR[ks][mf], BR[ks][nf], acc[(AI) + mf][(BJ) + nf], 0, 0, 0);

    for (int t = 0; t < NT; ++t) {
        const unsigned tb = (unsigned)(t & 1) << 16;
        const unsigned ta = tb ^ 0x10000u;
        const bool doS = (t < NT - 1);

        // ================= section A =================
        if (doS) {
            #pragma unroll
            for (int hh = 0; hh < 2; ++hh) {
                __builtin_amdgcn_global_load_lds(GLOBAL_CAST(asrc[hh][0]), LDS_CAST(lds + (ta | adst[hh][0])), 16, 0, 0);
                __builtin_amdgcn_global_load_lds(GLOBAL_CAST(asrc[hh][1]), LDS_CAST(lds + (ta | adst[hh][1])), 16, 0, 0);
            }
        }
        #pragma unroll
        for (int ks = 0; ks < 2; ++ks) {
            #pragma unroll
            for (int nf = 0; nf < 2; ++nf) b0[ks][nf] = RDB(ks, nf, 0);
            #pragma unroll
            for (int mf = 0; mf < 4; ++mf) a[ks][mf] = RDA(ks, mf, 0);
        }
        __builtin_amdgcn_s_setprio(1);
        MFMA16(a, b0, 0, 0)
        __builtin_amdgcn_s_setprio(0);

        if (doS) {
            #pragma unroll
            for (int hh = 0; hh < 2; ++hh) {
                __builtin_amdgcn_global_load_lds(GLOBAL_CAST(bsrc[hh][0]), LDS_CAST(lds + (ta | bdst[hh][0])), 16, 0, 0);
                __builtin_amdgcn_global_load_lds(GLOBAL_CAST(bsrc[hh][1]), LDS_CAST(lds + (ta | bdst[hh][1])), 16, 0, 0);
            }
        }
        #pragma unroll
        for (int ks = 0; ks < 2; ++ks)
            #pragma unroll
            for (int nf = 0; nf < 2; ++nf) b1[ks][nf] = RDB(ks, nf, 4096);
        __builtin_amdgcn_s_setprio(1);
        MFMA16(a, b1, 0, 2)
        __builtin_amdgcn_s_setprio(0);

        __builtin_amdgcn_s_barrier();

        // ================= section B =================
        #pragma unroll
        for (int ks = 0; ks < 2; ++ks)
            #pragma unroll
            for (int mf = 0; mf < 4; ++mf) a[ks][mf] = RDA(ks, mf, 8192);
        __builtin_amdgcn_s_setprio(1);
        MFMA16(a, b1, 4, 2)
        MFMA16(a, b0, 4, 0)
        __builtin_amdgcn_s_setprio(0);

        // advance stage streams (BK i8 = 128 B)
        #pragma unroll
        for (int hh = 0; hh < 2; ++hh) {
            asrc[hh][0] += BK; asrc[hh][1] += BK;
            bsrc[hh][0] += BK; bsrc[hh][1] += BK;
        }
        asm volatile("s_waitcnt vmcnt(0)" ::: "memory");
        __builtin_amdgcn_sched_barrier(0);
        __builtin_amdgcn_s_barrier();
    }
    #undef RDA
    #undef RDB
    #undef MFMA16

    // epilogue: out = sx[m]*scale[n]*acc + bias[n]
    // D layout: col = lane&15, row = (lane>>4)*4 + r
    float sxv[32];
    #pragma unroll
    for (int mf = 0; mf < 8; ++mf)
        #pragma unroll
        for (int r = 0; r < 4; ++r)
            sxv[mf * 4 + r] = sx[arow0 + wm * 128 + mf * 16 + kh * 4 + r];

    #pragma unroll
    for (int nf = 0; nf < 4; ++nf) {
        const int gn = brow0 + wn * 64 + nf * 16 + lr;
        const float sc = scale[gn];
        const float bs = bias[gn];
        #pragma unroll
        for (int mf = 0; mf < 8; ++mf) {
            const size_t gm = (size_t)arow0 + wm * 128 + mf * 16 + kh * 4;
            #pragma unroll
            for (int r = 0; r < 4; ++r)
                out[(gm + r) * (size_t)N + gn] =
                    (float)acc[mf][nf][r] * (sxv[mf * 4 + r] * sc) + bs;
        }
    }
}

// ---------------------------------------------------------------------------
// Fallback: fp32 smem-tiled GEMM, quantize on the fly.
// ---------------------------------------------------------------------------
__global__ __launch_bounds__(256) void fb_gemm_kernel(
    const float* __restrict__ X, const float* __restrict__ W,
    const float* __restrict__ scale, const float* __restrict__ bias,
    float* __restrict__ out, int M, int N, int K)
{
    __shared__ float xs[16][16];
    __shared__ float qs[16][17];
    const int tx = threadIdx.x & 15, ty = threadIdx.x >> 4;
    const int m = blockIdx.y * 16 + ty;
    const int n = blockIdx.x * 16 + tx;
    const int nrow = blockIdx.x * 16 + ty;
    const int mL = min(m, M - 1);
    const int nrowL = min(nrow, N - 1);
    const float thr = scale[nrowL] * 0.75f;
    float acc = 0.f;
    for (int k0 = 0; k0 < K; k0 += 16) {
        xs[ty][tx] = X[(size_t)mL * K + k0 + tx];
        const float w = W[(size_t)nrowL * K + k0 + tx];
        qs[ty][tx] = (w >= thr) ? 1.f : ((w <= -thr) ? -1.f : 0.f);
        __syncthreads();
        #pragma unroll
        for (int kk = 0; kk < 16; ++kk) acc += xs[ty][kk] * qs[tx][kk];
        __syncthreads();
    }
    if (m < M && n < N) out[(size_t)m * N + n] = scale[n] * acc + bias[n];
}

// ---------------------------------------------------------------------------
extern "C" void kernel_launch(void* const* d_in, const int* in_sizes, int n_in,
                              void* d_out, int out_size, void* d_ws, size_t ws_size,
                              hipStream_t stream)
{
    const float* x    = (const float*)d_in[0];
    const float* w    = (const float*)d_in[1];
    const float* bias = (const float*)d_in[2];
    float* out = (float*)d_out;

    const int N = in_sizes[2];             // OUT
    const int K = in_sizes[1] / N;         // IN
    const int M = in_sizes[0] / K;         // B

    const size_t scOff = 0;
    const size_t sxOff = (scOff + (size_t)N * 4 + 255) & ~(size_t)255;
    const size_t qOff  = (sxOff + (size_t)M * 4 + 255) & ~(size_t)255;
    const size_t xqOff = (qOff + (size_t)N * K + 255) & ~(size_t)255;
    const size_t need  = xqOff + (size_t)M * K;

    float* scale = (float*)((char*)d_ws + scOff);

    const bool fast = (ws_size >= need) &&
                      (M % BM == 0) && (N % BN == 0) && (K % BK == 0) &&
                      ((K & 3) == 0) && (K / BK >= 4) &&
                      (((M / BM) * (N / BN)) % 8 == 0);

    if (fast) {
        float* sx        = (float*)((char*)d_ws + sxOff);
        signed char* q   = (signed char*)((char*)d_ws + qOff);
        signed char* xq  = (signed char*)((char*)d_ws + xqOff);

        scale_quant_kernel<<<N, 256, 0, stream>>>(w, scale, q, K);
        x_quant_kernel<<<M, 256, 0, stream>>>(x, sx, xq, K);

        const int grid = (M / BM) * (N / BN);
        gemm256_i8_kernel<<<grid, 512, 0, stream>>>(xq, q, sx, scale, bias, out, M, N, K);
    } else {
        scale_quant_kernel<<<N, 256, 0, stream>>>(w, scale, nullptr, K);
        dim3 g((N + 15) / 16, (M + 15) / 16);
        fb_gemm_kernel<<<g, 256, 0, stream>>>(x, w, scale, bias, out, M, N, K);
    }
}